// Round 10
// baseline (39.655 us; speedup 1.0000x reference)
//
#include <hip/hip_runtime.h>
#include <hip/hip_fp16.h>
#include <hip/hip_bf16.h>

#define NN 256
#define AA 1024
#define JJ 4096          // B*C
#define OUTW 1152        // A + B

typedef __attribute__((ext_vector_type(8))) short short8v;
typedef __attribute__((ext_vector_type(4))) float floatx4;

__device__ __forceinline__ unsigned f2bf(float f) {
    __hip_bfloat16 h = __float2bfloat16(f);   // RNE hardware convert
    return (unsigned)*(unsigned short*)&h;
}

struct Pref {              // one prefetch set (named fields -> static indexing)
    float4 x0, x1, x2, x3;
    float t0, t1;
};

// ---------------------------------------------------------------------------
// fused: ONE launch, ZERO cross-block communication (r7 proved grid-barrier
// ruinous; r2..r8 proved multi-launch costs ~8-12us of serialized gaps).
// Grid 256 x 1024 thr (16 waves, 1 block/CU). Block (b = bid&127, h = bid>>7):
//   phase 0: out[bid][0:1024] = x[bid]
//   phase A: M_b[256][32] = x @ T[:, b*32..+32) -- full M_b per block
//            (x2 GEMM redundancy across h; only 4.2 GF total, trivial).
//            16 k-chunks of 64; inline f32->bf16 staging; prefetch distance 2;
//            RAW s_barrier + lgkmcnt(0)-only (T4): global loads stay in
//            flight across chunks (they target registers, so no cross-thread
//            visibility needed -- only LDS writes need the lgkm wait).
//            M_b goes straight from accumulators to LDS: no M global traffic.
//   phase B: o[n][b] = sum_m exp(-L1(M_b[n],M_b[m])) for n in h-half.
// LDS: xs 32K + ts 4K + Mb 16K + red 4K = 56 KB (static-safe).
// XOR swizzle byte ^= ((row&7)<<4) on write AND read everywhere (rule 21).
// ---------------------------------------------------------------------------
__global__ __launch_bounds__(1024) void fused(const float* __restrict__ x,
                                              const float* __restrict__ T,
                                              float* __restrict__ out) {
    __shared__ unsigned short xs[256 * 64];   // 32 KB  [n][k] swizzled
    __shared__ unsigned short ts[32 * 64];    // 4 KB   [j][k] swizzled
    __shared__ __half Mb[256][32];            // 16 KB
    __shared__ float red[8][128];             // 4 KB

    const int bid = blockIdx.x;
    const int b = bid & 127;
    const int h = bid >> 7;
    const int tid = threadIdx.x;
    const int lane = tid & 63;
    const int w = tid >> 6;                   // 0..15

    // ---- phase 0: copy x row 'bid' into out ----
    out[(size_t)bid * OUTW + tid] = x[(size_t)bid * AA + tid];

    // ---- staging assignments ----
    const int xr = tid >> 2;                  // x row 0..255
    const int kq = (tid & 3) * 16;            // k elem offset within chunk
    const float* xp = x + (size_t)xr * AA + kq;
    const int xsw = (xr & 7) << 4;
    const int xW0 = xr * 128 + ((kq * 2) ^ xsw);
    const int xW1 = xr * 128 + ((kq * 2 + 16) ^ xsw);

    const int tj = tid & 31;                  // T col 0..31
    const int tk2 = tid >> 5;                 // k-pair 0..31
    const float* tp = T + (size_t)(tk2 * 2) * JJ + b * 32 + tj;
    const int tW = tj * 128 + ((tk2 * 4) ^ ((tj & 7) << 4));

    // ---- compute assignments: wave w owns rows 16w..16w+15, both col-halves
    const int rf = lane & 15;
    const int g = lane >> 4;
    const int fsw = (rf & 7) << 4;
    const int aRow = (w * 16 + rf) * 128;
    const int b0Row = rf * 128;
    const int b1Row = (16 + rf) * 128;
    const int k0 = (g * 16) ^ fsw;            // ks=0 byte offset
    const int k1 = (64 + g * 16) ^ fsw;       // ks=1

    floatx4 acc0 = {0.f, 0.f, 0.f, 0.f};
    floatx4 acc1 = {0.f, 0.f, 0.f, 0.f};

    Pref A, B;

    auto LOADSET = [&](Pref& S, int C) {
        const float* xq = xp + C * 64;
        S.x0 = *(const float4*)(xq);
        S.x1 = *(const float4*)(xq + 4);
        S.x2 = *(const float4*)(xq + 8);
        S.x3 = *(const float4*)(xq + 12);
        const float* tq = tp + (size_t)C * 64 * JJ;
        S.t0 = tq[0];
        S.t1 = tq[JJ];
    };

    auto STAGE = [&](const Pref& S) {
        uint4 pa;
        pa.x = f2bf(S.x0.x) | (f2bf(S.x0.y) << 16);
        pa.y = f2bf(S.x0.z) | (f2bf(S.x0.w) << 16);
        pa.z = f2bf(S.x1.x) | (f2bf(S.x1.y) << 16);
        pa.w = f2bf(S.x1.z) | (f2bf(S.x1.w) << 16);
        *(uint4*)((char*)xs + xW0) = pa;
        pa.x = f2bf(S.x2.x) | (f2bf(S.x2.y) << 16);
        pa.y = f2bf(S.x2.z) | (f2bf(S.x2.w) << 16);
        pa.z = f2bf(S.x3.x) | (f2bf(S.x3.y) << 16);
        pa.w = f2bf(S.x3.z) | (f2bf(S.x3.w) << 16);
        *(uint4*)((char*)xs + xW1) = pa;
        *(unsigned*)((char*)ts + tW) = f2bf(S.t0) | (f2bf(S.t1) << 16);
    };

    auto COMPUTE = [&]() {
        short8v a0 = *(const short8v*)((char*)xs + aRow + k0);
        short8v v0 = *(const short8v*)((char*)ts + b0Row + k0);
        short8v v1 = *(const short8v*)((char*)ts + b1Row + k0);
        acc0 = __builtin_amdgcn_mfma_f32_16x16x32_bf16(a0, v0, acc0, 0, 0, 0);
        acc1 = __builtin_amdgcn_mfma_f32_16x16x32_bf16(a0, v1, acc1, 0, 0, 0);
        short8v a1 = *(const short8v*)((char*)xs + aRow + k1);
        short8v u0 = *(const short8v*)((char*)ts + b0Row + k1);
        short8v u1 = *(const short8v*)((char*)ts + b1Row + k1);
        acc0 = __builtin_amdgcn_mfma_f32_16x16x32_bf16(a1, u0, acc0, 0, 0, 0);
        acc1 = __builtin_amdgcn_mfma_f32_16x16x32_bf16(a1, u1, acc1, 0, 0, 0);
    };

    LOADSET(A, 0);
    LOADSET(B, 1);

#pragma unroll 1
    for (int c = 0; c < 16; c += 2) {
        __builtin_amdgcn_s_barrier();          // all waves done with buf reads
        STAGE(A);
        if (c + 2 < 16) LOADSET(A, c + 2);     // refill set A (2 chunks ahead)
        asm volatile("s_waitcnt lgkmcnt(0)" ::: "memory");  // my LDS writes done
        __builtin_amdgcn_sched_barrier(0);
        __builtin_amdgcn_s_barrier();          // staged data visible to all
        COMPUTE();

        __builtin_amdgcn_s_barrier();
        STAGE(B);
        if (c + 3 < 16) LOADSET(B, c + 3);
        asm volatile("s_waitcnt lgkmcnt(0)" ::: "memory");
        __builtin_amdgcn_sched_barrier(0);
        __builtin_amdgcn_s_barrier();
        COMPUTE();
    }

    // ---- M_b -> LDS (C/D layout: col = lane&15, row = (lane>>4)*4 + reg) ----
#pragma unroll
    for (int r = 0; r < 4; ++r) {
        Mb[w * 16 + g * 4 + r][rf] = __float2half(acc0[r]);
        Mb[w * 16 + g * 4 + r][16 + rf] = __float2half(acc1[r]);
    }
    __syncthreads();   // full drain fine here (once)

    // ---- phase B: pairwise. 1024 thr = 128 n x 8 m-groups ----
    const int nl = tid & 127;
    const int mq = tid >> 7;                  // uniform per wave
    const int n = h * 128 + nl;

    union u4h { uint4 u; __half2 hh[4]; };
    u4h mv[4];
#pragma unroll
    for (int i = 0; i < 4; ++i) mv[i].u = *(const uint4*)&Mb[n][i * 8];

    float o = 0.f;
    const int m0 = mq * 32;
#pragma unroll 4
    for (int m = m0; m < m0 + 32; ++m) {
        u4h rv[4];
#pragma unroll
        for (int i = 0; i < 4; ++i) rv[i].u = *(const uint4*)&Mb[m][i * 8];
        __half2 a0 = __habs2(__hsub2(mv[0].hh[0], rv[0].hh[0]));
        __half2 a1 = __habs2(__hsub2(mv[0].hh[1], rv[0].hh[1]));
        __half2 a2 = __habs2(__hsub2(mv[0].hh[2], rv[0].hh[2]));
        __half2 a3 = __habs2(__hsub2(mv[0].hh[3], rv[0].hh[3]));
#pragma unroll
        for (int i = 1; i < 4; ++i) {
            a0 = __hadd2(a0, __habs2(__hsub2(mv[i].hh[0], rv[i].hh[0])));
            a1 = __hadd2(a1, __habs2(__hsub2(mv[i].hh[1], rv[i].hh[1])));
            a2 = __hadd2(a2, __habs2(__hsub2(mv[i].hh[2], rv[i].hh[2])));
            a3 = __hadd2(a3, __habs2(__hsub2(mv[i].hh[3], rv[i].hh[3])));
        }
        __half2 s = __hadd2(__hadd2(a0, a1), __hadd2(a2, a3));
        float2 lf = __half22float2(s);
        o += __expf(-(lf.x + lf.y));
    }

    red[mq][nl] = o;
    __syncthreads();
    if (tid < 128) {
        float s = 0.f;
#pragma unroll
        for (int q2 = 0; q2 < 8; ++q2) s += red[q2][tid];
        out[(size_t)(h * 128 + tid) * OUTW + AA + b] = s;
    }
}

// ===========================================================================
extern "C" void kernel_launch(void* const* d_in, const int* in_sizes, int n_in,
                              void* d_out, int out_size, void* d_ws, size_t ws_size,
                              hipStream_t stream) {
    const float* x = (const float*)d_in[0];
    const float* T = (const float*)d_in[1];
    float* out = (float*)d_out;

    fused<<<256, 1024, 0, stream>>>(x, T, out);
}